// Round 5
// baseline (209.352 us; speedup 1.0000x reference)
//
#include <hip/hip_runtime.h>

// MeshTokenizer: B=64, NV=8192, NF=16384.
// Outputs concatenated flat as float32:
//   [0] input_ids        64 x 163841   @ 0
//   [1] attention_mask   64 x 163841   @ 10485824   (ALL ones -> pure fill)
//   [2] codes            64x16384x3x3  @ 20971648
//   [3] discrete_face_coords (==codes) @ 30408832
//   [4] recon_faces      64x1x3x3      @ 39846016
// 159.4 MB writes + ~20 MB reads -> ~28 us write-roofline @6.5 TB/s.
//
// R5 experiment: ONE write stream per block (role = blk&3: ids / mask-fill /
// c1 / c2) to test whether 4-way store-stream interleaving was throttling
// effective HBM write BW vs the harness fill's single-stream 6.5 TB/s.
// Pass A (unchanged): per-vertex packed codes -> 32 KB/batch L1-resident table.

#define B_      64
#define NV_     8192
#define NF_     16384
#define ROW_    (NF_ * 10 + 1)   // 163841 (odd stride -> per-batch dword phase b&3)
#define OFF_IDS   ((size_t)0)
#define OFF_MASK  ((size_t)10485824)
#define OFF_C1    ((size_t)20971648)
#define OFF_C2    ((size_t)30408832)
#define OFF_REC   ((size_t)39846016)

typedef float vf4 __attribute__((ext_vector_type(4)));

__device__ __forceinline__ float disc1(float x) {
    // (x-LO)/(HI-LO)*128 - 0.5 == (x+1)*64 - 0.5 bit-exactly; round-half-even
    float r = rintf((x + 1.0f) * 64.0f - 0.5f);
    return fminf(fmaxf(r, 0.0f), 127.0f);
}

// ---- Pass A: per-vertex discretize + pack (64*8192 = 524288 verts) ----
__global__ __launch_bounds__(256) void pack_verts_kernel(
        const float* __restrict__ verts,
        unsigned int* __restrict__ packed) {
    const int g = blockIdx.x * 256 + threadIdx.x;
    const float* vp = verts + (size_t)g * 3;
    const unsigned int c0 = (unsigned int)disc1(vp[0]);
    const unsigned int c1 = (unsigned int)disc1(vp[1]);
    const unsigned int c2 = (unsigned int)disc1(vp[2]);
    packed[g] = c0 | (c1 << 8) | (c2 << 16);
}

// ---- Pass B: 16384 blocks; role = blk&3 (block-uniform, no divergence),
// sub = blk>>2 picks (batch, face-range). Same-sub blocks are adjacent ->
// same XCD -> faces/table reads L2-shared across the 3 gather roles.
__global__ __launch_bounds__(256) void mesh_split_kernel(
        const unsigned int* __restrict__ packed,
        const int*          __restrict__ faces,
        float*              __restrict__ out) {
    const int t    = threadIdx.x;
    const int role = blockIdx.x & 3;
    const int sub  = blockIdx.x >> 2;    // 0..4095
    const int b    = sub >> 6;
    const int j0   = (sub & 63) << 8;

    // ---- role 1: attention_mask pure fill (4096 subs x 2560 floats exact) ----
    if (role == 1) {
        const vf4 ones = {1.0f, 1.0f, 1.0f, 1.0f};
        vf4* m4 = (vf4*)(out + OFF_MASK) + (size_t)sub * 640;
        for (int f4 = t; f4 < 640; f4 += 256)
            __builtin_nontemporal_store(ones, m4 + f4);
        return;
    }

    __shared__ __align__(16) float s_buf[2564];   // ids needs 2564, codes 2304

    // ---- gather: 3 packed dwords per face ----
    const int j = j0 + t;
    const int* fp = faces + ((size_t)b * NF_ + j) * 3;
    const unsigned int* pb = packed + (size_t)b * NV_;
    float code_f[9];
    #pragma unroll
    for (int vi = 0; vi < 3; ++vi) {
        const unsigned int pk = pb[fp[vi]];
        code_f[vi * 3 + 0] = (float)(pk & 127u);
        code_f[vi * 3 + 1] = (float)((pk >> 8) & 127u);
        code_f[vi * 3 + 2] = (float)((pk >> 16) & 127u);
    }

    if (role == 0) {
        // ---- input_ids: contiguous 2560-float span at S, phase-aligned ----
        const size_t S  = (size_t)b * ROW_ + (size_t)j0 * 10;
        const int    p  = (int)(S & 3);           // == b & 3
        const int    pp = (4 - p) & 3;

        s_buf[p + t * 10] = (j == 0) ? -1.0f : 128.0f;   // sep of j-1 / lead pad
        #pragma unroll
        for (int k = 0; k < 9; ++k)
            s_buf[p + t * 10 + 1 + k] = code_f[k];
        __syncthreads();

        float* out_ids = out + OFF_IDS;
        const size_t A   = S + pp;
        const int    nf4 = (p == 0) ? 640 : 639;
        const int    lb  = (p == 0) ? 0 : 1;
        const vf4*   s4  = (const vf4*)s_buf;
        vf4* ids4 = (vf4*)(out_ids + A);
        for (int f4 = t; f4 < nf4; f4 += 256)
            __builtin_nontemporal_store(s4[lb + f4], ids4 + f4);
        if (t < pp)                    out_ids[S + t] = s_buf[p + t];
        if (t >= 4 && t < 4 + p)       out_ids[S + 2560 - p + (t - 4)] = s_buf[2560 + (t - 4)];
        if (t == 0 && j0 == NF_ - 256) out_ids[(size_t)b * ROW_ + (ROW_ - 1)] = -1.0f;
    } else {
        // ---- roles 2/3: codes stream (naturally 16B-aligned) ----
        #pragma unroll
        for (int k = 0; k < 9; ++k)
            s_buf[t * 9 + k] = code_f[k];
        __syncthreads();

        float* dst = out + ((role == 2) ? OFF_C1 : OFF_C2);
        const size_t baseC = ((size_t)b * NF_ + j0) * 9;
        const vf4* sc4 = (const vf4*)s_buf;
        vf4* cp = (vf4*)(dst + baseC);
        for (int f4 = t; f4 < 576; f4 += 256)
            __builtin_nontemporal_store(sc4[f4], cp + f4);

        if (role == 2 && j0 == 0 && t == 0) {   // face 0 -> recon_faces
            float* out_rec = out + OFF_REC;
            #pragma unroll
            for (int k = 0; k < 9; ++k)
                out_rec[b * 9 + k] = (code_f[k] + 0.5f) * 0.015625f - 1.0f;
        }
    }
}

extern "C" void kernel_launch(void* const* d_in, const int* in_sizes, int n_in,
                              void* d_out, int out_size, void* d_ws, size_t ws_size,
                              hipStream_t stream) {
    const float*  verts  = (const float*)d_in[0];
    const int*    faces  = (const int*)d_in[1];
    float*        out    = (float*)d_out;
    unsigned int* packed = (unsigned int*)d_ws;   // 2 MB: 64*8192 uints

    pack_verts_kernel<<<dim3(B_ * NV_ / 256), dim3(256), 0, stream>>>(verts, packed);
    mesh_split_kernel<<<dim3(4 * B_ * (NF_ / 256)), dim3(256), 0, stream>>>(packed, faces, out);
}

// Round 6
// 179.690 us; speedup vs baseline: 1.1651x; 1.1651x over previous
//
#include <hip/hip_runtime.h>

// MeshTokenizer: B=64, NV=8192, NF=16384.
// Outputs concatenated flat as float32:
//   [0] input_ids        64 x 163841   @ 0
//   [1] attention_mask   64 x 163841   @ 10485824   (all ones)
//   [2] codes            64x16384x3x3  @ 20971648
//   [3] discrete_face_coords (==codes) @ 30408832
//   [4] recon_faces      64x1x3x3      @ 39846016
// 159.4 MB writes + ~20 MB reads -> ~27 us write-roofline @6.5 TB/s.
//
// R6: R4 structure (best so far, 185.6us). Changes vs R4:
//  - drop nontemporal on all stores (R3 changed vec+nt together; nt never
//    tested in isolation — plain stores let L2 absorb the write burst)
//  - mask stores (input-independent) issued before the gather-dependent
//    LDS staging, so stores flow while gathers are in flight
// Pass A: per-vertex packed codes -> 32 KB/batch L1-resident table (won -4.8us in R4).

#define B_      64
#define NV_     8192
#define NF_     16384
#define ROW_    (NF_ * 10 + 1)   // 163841 (odd stride -> per-batch dword phase b&3)
#define OFF_IDS   ((size_t)0)
#define OFF_MASK  ((size_t)10485824)
#define OFF_C1    ((size_t)20971648)
#define OFF_C2    ((size_t)30408832)
#define OFF_REC   ((size_t)39846016)

typedef float vf4 __attribute__((ext_vector_type(4)));

__device__ __forceinline__ float disc1(float x) {
    // (x-LO)/(HI-LO)*128 - 0.5 == (x+1)*64 - 0.5 bit-exactly; round-half-even
    float r = rintf((x + 1.0f) * 64.0f - 0.5f);
    return fminf(fmaxf(r, 0.0f), 127.0f);
}

// ---- Pass A: per-vertex discretize + pack (64*8192 = 524288 verts) ----
__global__ __launch_bounds__(256) void pack_verts_kernel(
        const float* __restrict__ verts,
        unsigned int* __restrict__ packed) {
    const int g = blockIdx.x * 256 + threadIdx.x;
    const float* vp = verts + (size_t)g * 3;
    const unsigned int c0 = (unsigned int)disc1(vp[0]);
    const unsigned int c1 = (unsigned int)disc1(vp[1]);
    const unsigned int c2 = (unsigned int)disc1(vp[2]);
    packed[g] = c0 | (c1 << 8) | (c2 << 16);
}

// ---- Pass B: one block = 256 consecutive faces of one batch. Thread t
// (face j) owns input_ids [j*10, j*10+9]; block span = contiguous 2560 floats
// at S = b*163841 + j0*10. Phase p = S&3 baked into LDS so global stores are
// 16B-aligned dwordx4; <=3 head + <=3 tail elems scalar.
__global__ __launch_bounds__(256) void mesh_tok_kernel(
        const unsigned int* __restrict__ packed,
        const int*          __restrict__ faces,
        float*              __restrict__ out) {
    const int t   = threadIdx.x;
    const int blk = blockIdx.x;
    const int b   = blk >> 6;            // batch
    const int j0  = (blk & 63) << 8;     // first face of this block
    const int j   = j0 + t;

    __shared__ __align__(16) float s_ids[2564];
    __shared__ __align__(16) float s_codes[2304];

    const size_t S  = (size_t)b * ROW_ + (size_t)j0 * 10;
    const int    p  = (int)(S & 3);                        // == b & 3
    const int    pp = (4 - p) & 3;
    const size_t A  = S + pp;                              // 16B-aligned start
    const int    nf4 = (p == 0) ? 640 : 639;
    const int    lb  = (p == 0) ? 0 : 1;

    float* out_ids  = out + OFF_IDS;
    float* out_mask = out + OFF_MASK;

    // ---- issue gather loads (face idx -> packed codes) ----
    const int* fp = faces + ((size_t)b * NF_ + j) * 3;
    const unsigned int* pb = packed + (size_t)b * NV_;
    const int i0 = fp[0], i1 = fp[1], i2 = fp[2];
    const unsigned int pk0 = pb[i0], pk1 = pb[i1], pk2 = pb[i2];

    // ---- mask: input-independent, store while gathers are in flight ----
    {
        const vf4 ones = {1.0f, 1.0f, 1.0f, 1.0f};
        vf4* mask4 = (vf4*)(out_mask + A);
        for (int f4 = t; f4 < nf4; f4 += 256) mask4[f4] = ones;
        if (t < pp)              out_mask[S + t] = 1.0f;
        if (t >= 4 && t < 4 + p) out_mask[S + 2560 - p + (t - 4)] = 1.0f;
        if (t == 0) {
            if (j0 == NF_ - 256) out_mask[(size_t)b * ROW_ + (ROW_ - 1)] = 1.0f;
        }
    }

    // ---- unpack codes ----
    float code_f[9];
    const unsigned int pk[3] = {pk0, pk1, pk2};
    #pragma unroll
    for (int vi = 0; vi < 3; ++vi) {
        code_f[vi * 3 + 0] = (float)(pk[vi] & 127u);
        code_f[vi * 3 + 1] = (float)((pk[vi] >> 8) & 127u);
        code_f[vi * 3 + 2] = (float)((pk[vi] >> 16) & 127u);
    }

    // ---- stage ids (phase-shifted) + codes ----
    s_ids[p + t * 10] = (j == 0) ? -1.0f : 128.0f;         // sep of j-1 / lead pad
    #pragma unroll
    for (int k = 0; k < 9; ++k) {
        s_ids[p + t * 10 + 1 + k] = code_f[k];
        s_codes[t * 9 + k]        = code_f[k];
    }
    __syncthreads();

    // ---- ids: aligned vf4 stores ----
    {
        const vf4* s4 = (const vf4*)s_ids;
        vf4* ids4 = (vf4*)(out_ids + A);
        for (int f4 = t; f4 < nf4; f4 += 256) ids4[f4] = s4[lb + f4];
        if (t < pp)              out_ids[S + t] = s_ids[p + t];
        if (t >= 4 && t < 4 + p) out_ids[S + 2560 - p + (t - 4)] = s_ids[2560 + (t - 4)];
    }

    // ---- codes x2: naturally 16B-aligned ----
    const size_t baseC = ((size_t)b * NF_ + j0) * 9;
    const vf4* sc4 = (const vf4*)s_codes;
    vf4* c1p = (vf4*)(out + OFF_C1 + baseC);
    vf4* c2p = (vf4*)(out + OFF_C2 + baseC);
    for (int f4 = t; f4 < 576; f4 += 256) {
        vf4 v = sc4[f4];
        c1p[f4] = v;
        c2p[f4] = v;
    }

    // ---- final ids pad + recon_faces ----
    if (t == 0) {
        if (j0 == NF_ - 256)
            out_ids[(size_t)b * ROW_ + (ROW_ - 1)] = -1.0f;
        if (j0 == 0) {  // thread 0 of first block holds face 0's codes
            float* out_rec = out + OFF_REC;
            #pragma unroll
            for (int k = 0; k < 9; ++k)
                out_rec[b * 9 + k] = (code_f[k] + 0.5f) * 0.015625f - 1.0f;
        }
    }
}

extern "C" void kernel_launch(void* const* d_in, const int* in_sizes, int n_in,
                              void* d_out, int out_size, void* d_ws, size_t ws_size,
                              hipStream_t stream) {
    const float*  verts  = (const float*)d_in[0];
    const int*    faces  = (const int*)d_in[1];
    float*        out    = (float*)d_out;
    unsigned int* packed = (unsigned int*)d_ws;   // 2 MB: 64*8192 uints

    pack_verts_kernel<<<dim3(B_ * NV_ / 256), dim3(256), 0, stream>>>(verts, packed);
    mesh_tok_kernel  <<<dim3(B_ * (NF_ / 256)), dim3(256), 0, stream>>>(packed, faces, out);
}